// Round 8
// baseline (341.472 us; speedup 1.0000x reference)
//
#include <hip/hip_runtime.h>

typedef __bf16 bf16;
typedef __attribute__((ext_vector_type(4))) float  f32x4;
typedef __attribute__((ext_vector_type(8))) short  s16x8;   // MFMA bf16 A/B fragment
typedef __attribute__((ext_vector_type(8))) __bf16 bf16x8;
typedef __attribute__((ext_vector_type(4))) __bf16 bf16x4;

#define KD    576     // d_model = GEMM K
#define N1P   1792    // padded qkv cols (real 1728 = 576 q + 1152 kv)

#define BAR()    __builtin_amdgcn_s_barrier()
#define SCHED0() __builtin_amdgcn_sched_barrier(0)

__device__ __forceinline__ void gload_lds16(const void* g, void* l) {
  __builtin_amdgcn_global_load_lds((const __attribute__((address_space(1))) void*)g,
                                   (__attribute__((address_space(3))) void*)l, 16, 0, 0);
}

// ---------------- RMSNorm: x (f32) -> xn (bf16) ----------------
__global__ __launch_bounds__(256) void rmsnorm_k(const float* __restrict__ x,
                                                 bf16* __restrict__ xn) {
  const int lane = threadIdx.x & 63;
  const int row  = blockIdx.x * 4 + (threadIdx.x >> 6);
  const float4* xr = (const float4*)(x + (size_t)row * KD);
  float4 v0 = xr[lane];
  float4 v1 = xr[lane + 64];
  float4 v2 = {0.f, 0.f, 0.f, 0.f};
  if (lane < 16) v2 = xr[lane + 128];
  float ss = v0.x*v0.x + v0.y*v0.y + v0.z*v0.z + v0.w*v0.w
           + v1.x*v1.x + v1.y*v1.y + v1.z*v1.z + v1.w*v1.w
           + v2.x*v2.x + v2.y*v2.y + v2.z*v2.z + v2.w*v2.w;
#pragma unroll
  for (int off = 32; off > 0; off >>= 1) ss += __shfl_xor(ss, off, 64);
  const float inv = 1.0f / sqrtf(ss * (1.0f / 576.0f) + 1e-6f);
  bf16* orow = xn + (size_t)row * KD;
  bf16x4 o0 = {(bf16)(v0.x*inv), (bf16)(v0.y*inv), (bf16)(v0.z*inv), (bf16)(v0.w*inv)};
  *(bf16x4*)(orow + lane * 4) = o0;
  bf16x4 o1 = {(bf16)(v1.x*inv), (bf16)(v1.y*inv), (bf16)(v1.z*inv), (bf16)(v1.w*inv)};
  *(bf16x4*)(orow + (lane + 64) * 4) = o1;
  if (lane < 16) {
    bf16x4 o2 = {(bf16)(v2.x*inv), (bf16)(v2.y*inv), (bf16)(v2.z*inv), (bf16)(v2.w*inv)};
    *(bf16x4*)(orow + (lane + 128) * 4) = o2;
  }
}

// ---------------- RoPE cos/sin table: [2048][32] each ----------------
__global__ void ropetab_k(float* __restrict__ ctab, float* __restrict__ stab) {
  const int s = blockIdx.x * blockDim.x + threadIdx.x;
  if (s >= 2048) return;
  const float l2r = 0.4152410118609203f;  // log2(10000)/32
#pragma unroll 1
  for (int i = 0; i < 32; ++i) {
    const float theta = exp2f(-(float)i * l2r);
    const float f = (float)s * theta;
    float sv, cv;
    sincosf(f, &sv, &cv);
    ctab[s * 32 + i] = cv;
    stab[s * 32 + i] = sv;
  }
}

// -------- weights -> bf16: Wcat = [Wq;Wkv] padded to 1792 rows; Wo padded to 640 --------
__global__ __launch_bounds__(256) void wconv_k(const float* __restrict__ Wq,
                                               const float* __restrict__ Wkv,
                                               const float* __restrict__ Wo,
                                               bf16* __restrict__ wcat,
                                               bf16* __restrict__ wo) {
  const int idx = blockIdx.x * 256 + threadIdx.x;   // grid covers 1792*576 exactly
  {
    const int row = idx / 576;
    float v = 0.f;
    if (row < 576)       v = Wq[idx];
    else if (row < 1728) v = Wkv[idx - 331776];
    wcat[idx] = (bf16)v;
  }
  if (idx < 640 * 576) {
    float v = (idx < 331776) ? Wo[idx] : 0.f;
    wo[idx] = (bf16)v;
  }
}

// ---------------- GEMM1 (QKV): 256x256 tile, BK=64, 8 waves ----------------
// R6 counters: 90us, MfmaUtil 30%, VALUBusy 16%, Occupancy 17.8% (1 blk/CU, 2 waves/SIMD)
// -> machine idle ~54%: 9 barriers/K-tile in lockstep at 2 waves/SIMD is the stall.
// R7 change: MINIMAL barrier set derived from hazards. Staging writes only buf[nxt]
// (never read this iter); phases only read buf[cur]. So per K-tile only:
//   BAR1 (after boundary vmcnt: tile-t data visible to all waves)
//   BAR2 (after last phase: all reads of cur done before next iter stages into it)
// Waves free-run across phases; per-wave lgkmcnt(0)+sched_barrier still orders
// each wave's ds_reads before its MFMA cluster (rule #18).
// vmcnt ledger: at iter-t top after staging u0,u1(t+1): outstanding =
//   u2,u3(t) [4] + u0,u1(t+1) [4] = 8 -> vmcnt(4) drains exactly tile t.
__global__ __launch_bounds__(512, 2) void gemm8p_k(const bf16* __restrict__ A,
                                                   const bf16* __restrict__ Bw,
                                                   bf16* __restrict__ C,
                                                   int ntiles) {
  extern __shared__ char smem[];
  const int tid  = threadIdx.x;
  const int lane = tid & 63;
  const int wv   = tid >> 6;
  const int nwg = gridDim.x;          // % 8 == 0
  const int cpx = nwg >> 3;
  const int swz = (blockIdx.x & 7) * cpx + (blockIdx.x >> 3);
  const int mt = swz / ntiles;
  const int nt = swz - mt * ntiles;
  const int wMl = (wv >> 2) << 7;     // 0 / 128
  const int wNl = (wv & 3) << 6;      // 0 / 64 / 128 / 192

  const bf16* Ab = A  + (size_t)mt * 256 * KD;
  const bf16* Bb = Bw + (size_t)nt * 256 * KD;

  // per-thread staging source offsets (swizzled): unit u in {0,1}, rep q in {0,1}
  int off[4];
#pragma unroll
  for (int u = 0; u < 2; ++u)
#pragma unroll
    for (int q = 0; q < 2; ++q) {
      const int c = u * 1024 + q * 512 + tid;
      const int row = c >> 3, slot = c & 7;
      const int ks = slot ^ (row & 7);
      off[u * 2 + q] = row * KD + ks * 8;
    }

  // stage unit uu (0,1 = A-halves; 2,3 = B-halves) of K-tile with k-offset k0n into buffer bb
  auto stage_unit = [&](int uu, int k0n, int bb) {
    const int u = uu & 1;
#pragma unroll
    for (int q = 0; q < 2; ++q) {
      const int c = u * 1024 + q * 512 + tid;
      if (uu < 2) gload_lds16(Ab + off[u * 2 + q] + k0n, smem + bb * 65536 + c * 16);
      else        gload_lds16(Bb + off[u * 2 + q] + k0n, smem + bb * 65536 + 32768 + c * 16);
    }
  };

  f32x4 acc[8][4];
#pragma unroll
  for (int i = 0; i < 8; ++i)
#pragma unroll
    for (int j = 0; j < 4; ++j) { acc[i][j][0]=0.f; acc[i][j][1]=0.f; acc[i][j][2]=0.f; acc[i][j][3]=0.f; }

  // prologue: stage tile 0 fully into buf 0
#pragma unroll
  for (int uu = 0; uu < 4; ++uu) stage_unit(uu, 0, 0);

#pragma unroll 1
  for (int t = 0; t < 9; ++t) {
    const int cur = t & 1, nxt = cur ^ 1;
    const int k0n = (t + 1) * 64;
    if (t < 8) {
      stage_unit(0, k0n, nxt);
      stage_unit(1, k0n, nxt);
      asm volatile("s_waitcnt vmcnt(4)" ::: "memory");   // drains tile t exactly (ledger above)
    } else {
      asm volatile("s_waitcnt vmcnt(0)" ::: "memory");
    }
    BAR();                                               // BAR1: tile-t LDS visible to all
    const bf16* As = (const bf16*)(smem + cur * 65536);
    const bf16* Bs = (const bf16*)(smem + cur * 65536 + 32768);
    s16x8 bfrag[4][2];
#pragma unroll
    for (int p = 0; p < 4; ++p) {
      s16x8 afrag[2][2];
#pragma unroll
      for (int i2 = 0; i2 < 2; ++i2)
#pragma unroll
        for (int kk = 0; kk < 2; ++kk) {
          const int arow = wMl + (p * 2 + i2) * 16 + (lane & 15);
          const int aps  = ((kk << 2) + (lane >> 4)) ^ (arow & 7);
          afrag[i2][kk] = *(const s16x8*)(As + arow * 64 + aps * 8);
        }
      if (p == 0) {
#pragma unroll
        for (int j = 0; j < 4; ++j)
#pragma unroll
          for (int kk = 0; kk < 2; ++kk) {
            const int brow = wNl + j * 16 + (lane & 15);
            const int bps  = ((kk << 2) + (lane >> 4)) ^ (brow & 7);
            bfrag[j][kk] = *(const s16x8*)(Bs + brow * 64 + bps * 8);
          }
      }
      if (t < 8 && p < 2) stage_unit(2 + p, k0n, nxt);   // B-halves of t+1 spread across p0/p1
      asm volatile("s_waitcnt lgkmcnt(0)" ::: "memory");
      SCHED0();                                          // rule #18
      __builtin_amdgcn_s_setprio(1);
#pragma unroll
      for (int i2 = 0; i2 < 2; ++i2)
#pragma unroll
        for (int j = 0; j < 4; ++j)
#pragma unroll
          for (int kk = 0; kk < 2; ++kk)
            acc[p * 2 + i2][j] = __builtin_amdgcn_mfma_f32_16x16x32_bf16(
                afrag[i2][kk], bfrag[j][kk], acc[p * 2 + i2][j], 0, 0, 0);
      __builtin_amdgcn_s_setprio(0);
      SCHED0();
      // no inter-phase barrier: phases only read buf[cur]; staging only writes buf[nxt]
    }
    BAR();                                               // BAR2: reads of cur done before it
                                                         // becomes the staging target next iter
  }

  // epilogue: wave-private [64][72] LDS transpose (after final BAR2 -> all buf reads done),
  // fully unrolled (all acc indices static, rule #20), then 16B coalesced stores.
  bf16* ep = (bf16*)(smem + wv * 9216);
  const size_t crow0 = (size_t)(mt * 256 + wMl);
  const int    ccol0 = nt * 256 + wNl;
#pragma unroll
  for (int half = 0; half < 2; ++half) {
    asm volatile("s_waitcnt lgkmcnt(0)" ::: "memory"); SCHED0();
#pragma unroll
    for (int i = 0; i < 4; ++i)
#pragma unroll
      for (int j = 0; j < 4; ++j)
#pragma unroll
        for (int r = 0; r < 4; ++r) {
          const int row = i * 16 + ((lane >> 4) << 2) + r;
          ep[row * 72 + j * 16 + (lane & 15)] = (bf16)acc[half * 4 + i][j][r];
        }
    asm volatile("s_waitcnt lgkmcnt(0)" ::: "memory"); SCHED0();
#pragma unroll
    for (int it = 0; it < 8; ++it) {
      const int c = it * 64 + lane;
      const int row = c >> 3, c8 = c & 7;
      s16x8 v = *(const s16x8*)(ep + row * 72 + c8 * 8);
      *(s16x8*)(C + (crow0 + half * 64 + row) * (size_t)N1P + ccol0 + c8 * 8) = v;
    }
  }
}

// ---------------- GEMM2 (O-proj + identity): R2-validated 128x128 2-phase (CONTROL) ----
__global__ __launch_bounds__(256) void gemm_o_k(const bf16* __restrict__ A,
                                                const bf16* __restrict__ Bw,
                                                float* __restrict__ C,
                                                const float* __restrict__ ident,
                                                int ntiles) {
  __shared__ bf16 As[128 * 64];
  __shared__ bf16 Bs[128 * 64];
  const int tid  = threadIdx.x;
  const int lane = tid & 63;
  const int nwg = gridDim.x;
  const int cpx = nwg >> 3;
  const int swz = (blockIdx.x & 7) * cpx + (blockIdx.x >> 3);
  const int mt = swz / ntiles;
  const int nt = swz - mt * ntiles;
  const int wv = tid >> 6;
  const int wr = (wv >> 1) << 6;
  const int wc = (wv & 1) << 6;

  const size_t abase = (size_t)mt * 128 * KD;
  const size_t bbase = (size_t)nt * 128 * KD;

  f32x4 zero = {0.f, 0.f, 0.f, 0.f};
  f32x4 acc[4][4];
#pragma unroll
  for (int i = 0; i < 4; ++i)
#pragma unroll
    for (int j = 0; j < 4; ++j) acc[i][j] = zero;

  for (int kt = 0; kt < 9; ++kt) {
    const int k0 = kt * 64;
    __syncthreads();
#pragma unroll
    for (int r = 0; r < 4; ++r) {
      const int c   = r * 256 + tid;
      const int row = c >> 3;
      const int ks  = (c & 7) ^ (row & 7);
      gload_lds16(A + abase + (size_t)row * KD + k0 + ks * 8, As + c * 8);
    }
#pragma unroll
    for (int r = 0; r < 4; ++r) {
      const int c   = r * 256 + tid;
      const int row = c >> 3;
      const int ks  = (c & 7) ^ (row & 7);
      gload_lds16(Bw + bbase + (size_t)row * KD + k0 + ks * 8, Bs + c * 8);
    }
    __syncthreads();
#pragma unroll
    for (int kk = 0; kk < 2; ++kk) {
      s16x8 af[4], bq[4];
#pragma unroll
      for (int i = 0; i < 4; ++i) {
        const int arow = wr + i * 16 + (lane & 15);
        const int aps  = ((kk << 2) + (lane >> 4)) ^ (arow & 7);
        af[i] = *(const s16x8*)(As + arow * 64 + aps * 8);
      }
#pragma unroll
      for (int j = 0; j < 4; ++j) {
        const int brow = wc + j * 16 + (lane & 15);
        const int bps  = ((kk << 2) + (lane >> 4)) ^ (brow & 7);
        bq[j] = *(const s16x8*)(Bs + brow * 64 + bps * 8);
      }
#pragma unroll
      for (int i = 0; i < 4; ++i)
#pragma unroll
        for (int j = 0; j < 4; ++j)
          acc[i][j] = __builtin_amdgcn_mfma_f32_16x16x32_bf16(af[i], bq[j], acc[i][j], 0, 0, 0);
    }
  }
  const int rbase = mt * 128 + wr + ((lane >> 4) << 2);
  const int cbase = nt * 128 + wc + (lane & 15);
#pragma unroll
  for (int i = 0; i < 4; ++i)
#pragma unroll
    for (int j = 0; j < 4; ++j) {
      const int col = cbase + j * 16;
      if (col < 576) {
#pragma unroll
        for (int r = 0; r < 4; ++r) {
          const size_t o = (size_t)(rbase + i * 16 + r) * 576 + col;
          C[o] = acc[i][j][r] + ident[o];
        }
      }
    }
}

// ---------------- per-position head-mix attention (chunk-outer PV) (CONTROL) --------
__global__ __launch_bounds__(256) void attn2_k(const bf16* __restrict__ qkv,
                                               const float* __restrict__ ctab,
                                               const float* __restrict__ stab,
                                               bf16* __restrict__ attn) {
  const int tid = blockIdx.x * 256 + threadIdx.x;  // 0 .. 294911 exactly
  const int bs  = tid / 9;
  const int h   = tid - bs * 9;
  const int s   = bs & 2047;
  const bf16* qrow = qkv + (size_t)bs * N1P;

  float q[64];
#pragma unroll
  for (int c = 0; c < 8; ++c) {
    bf16x8 v = *(const bf16x8*)(qrow + h * 64 + c * 8);
#pragma unroll
    for (int e = 0; e < 8; ++e) q[c * 8 + e] = (float)v[e];
  }
  const float* cr = ctab + s * 32;
  const float* sr = stab + s * 32;
#pragma unroll
  for (int i = 0; i < 32; ++i) {
    const float cv = cr[i], sv = sr[i];
    const float a = q[2 * i], b = q[2 * i + 1];
    q[2 * i]     = a * cv - b * sv;
    q[2 * i + 1] = a * sv + b * cv;
  }
  const bf16* kvr = qrow + 576;
  float sc[9];
#pragma unroll
  for (int g = 0; g < 9; ++g) {
    const bf16* kg = kvr + g * 128;
    float d0 = 0.f, d1 = 0.f, d2 = 0.f, d3 = 0.f;
#pragma unroll
    for (int c = 0; c < 8; ++c) {
      bf16x8 v = *(const bf16x8*)(kg + c * 8);
      d0 += q[c*8+0] * (float)v[0];
      d1 += q[c*8+1] * (float)v[1];
      d2 += q[c*8+2] * (float)v[2];
      d3 += q[c*8+3] * (float)v[3];
      d0 += q[c*8+4] * (float)v[4];
      d1 += q[c*8+5] * (float)v[5];
      d2 += q[c*8+6] * (float)v[6];
      d3 += q[c*8+7] * (float)v[7];
    }
    sc[g] = (d0 + d1 + d2 + d3) * 0.125f;
  }
  float mx = sc[0];
#pragma unroll
  for (int g = 1; g < 9; ++g) mx = fmaxf(mx, sc[g]);
  float sum = 0.f;
#pragma unroll
  for (int g = 0; g < 9; ++g) { sc[g] = expf(sc[g] - mx); sum += sc[g]; }
  const float inv = 1.0f / sum;
#pragma unroll
  for (int g = 0; g < 9; ++g) sc[g] *= inv;

  const int b = bs >> 11;
  bf16* orow = attn + ((size_t)((b * 9 + h) * 2048 + s)) * 64;
#pragma unroll
  for (int c = 0; c < 8; ++c) {
    float o[8];
#pragma unroll
    for (int e = 0; e < 8; ++e) o[e] = 0.f;
#pragma unroll
    for (int g = 0; g < 9; ++g) {
      bf16x8 v = *(const bf16x8*)(kvr + g * 128 + 64 + c * 8);
#pragma unroll
      for (int e = 0; e < 8; ++e) o[e] += sc[g] * (float)v[e];
    }
    bf16x8 ov;
#pragma unroll
    for (int e = 0; e < 8; ++e) ov[e] = (bf16)o[e];
    *(bf16x8*)(orow + c * 8) = ov;
  }
}

// ---------------- launch ----------------
extern "C" void kernel_launch(void* const* d_in, const int* in_sizes, int n_in,
                              void* d_out, int out_size, void* d_ws, size_t ws_size,
                              hipStream_t stream) {
  const float* x   = (const float*)d_in[0];
  const float* Wq  = (const float*)d_in[1];
  const float* Wkv = (const float*)d_in[2];
  const float* Wo  = (const float*)d_in[3];

  char* ws = (char*)d_ws;
  const size_t o_xn   = 0;                       // 32768*576*2 (xn, later attn)
  const size_t o_wcat = o_xn   + 37748736;
  const size_t o_wo   = o_wcat + 2064384;
  const size_t o_ct   = o_wo   + 737280;
  const size_t o_st   = o_ct   + 262144;
  const size_t o_qkv  = o_st   + 262144;
  const size_t need   = o_qkv  + 117440512;      // ~158.5 MB
  if (ws_size < need) return;

  bf16*  xn   = (bf16*)(ws + o_xn);
  bf16*  attn = (bf16*)(ws + o_xn);              // alias: xn dead after GEMM1
  bf16*  wcat = (bf16*)(ws + o_wcat);
  bf16*  wo   = (bf16*)(ws + o_wo);
  float* ctab = (float*)(ws + o_ct);
  float* stab = (float*)(ws + o_st);
  bf16*  qkv  = (bf16*)(ws + o_qkv);

  hipFuncSetAttribute((const void*)gemm8p_k,
                      hipFuncAttributeMaxDynamicSharedMemorySize, 131072);

  rmsnorm_k<<<8192, 256, 0, stream>>>(x, xn);
  ropetab_k<<<32, 64, 0, stream>>>(ctab, stab);
  wconv_k<<<4032, 256, 0, stream>>>(Wq, Wkv, Wo, wcat, wo);
  // QKV: M=32768, N=1792, K=576 -> 128 x 7 tiles of 256x256
  gemm8p_k<<<896, 512, 131072, stream>>>(xn, wcat, qkv, 7);
  attn2_k<<<1152, 256, 0, stream>>>(qkv, ctab, stab, attn);
  // O-proj + identity: M=32768, N=640(masked 576), K=576
  gemm_o_k<<<1280, 256, 0, stream>>>(attn, wo, (float*)d_out, x, 5);
}

// Round 10
// 332.185 us; speedup vs baseline: 1.0280x; 1.0280x over previous
//
#include <hip/hip_runtime.h>

typedef __bf16 bf16;
typedef __attribute__((ext_vector_type(4))) float  f32x4;
typedef __attribute__((ext_vector_type(8))) short  s16x8;   // MFMA bf16 A/B fragment
typedef __attribute__((ext_vector_type(8))) __bf16 bf16x8;
typedef __attribute__((ext_vector_type(4))) __bf16 bf16x4;

#define KD    576     // d_model = GEMM K
#define N1P   1792    // padded qkv cols (real 1728 = 576 q + 1152 kv)

#define BAR()    __builtin_amdgcn_s_barrier()
#define SCHED0() __builtin_amdgcn_sched_barrier(0)

__device__ __forceinline__ void gload_lds16(const void* g, void* l) {
  __builtin_amdgcn_global_load_lds((const __attribute__((address_space(1))) void*)g,
                                   (__attribute__((address_space(3))) void*)l, 16, 0, 0);
}

// ---------------- RMSNorm: x (f32) -> xn (bf16) ----------------
__global__ __launch_bounds__(256) void rmsnorm_k(const float* __restrict__ x,
                                                 bf16* __restrict__ xn) {
  const int lane = threadIdx.x & 63;
  const int row  = blockIdx.x * 4 + (threadIdx.x >> 6);
  const float4* xr = (const float4*)(x + (size_t)row * KD);
  float4 v0 = xr[lane];
  float4 v1 = xr[lane + 64];
  float4 v2 = {0.f, 0.f, 0.f, 0.f};
  if (lane < 16) v2 = xr[lane + 128];
  float ss = v0.x*v0.x + v0.y*v0.y + v0.z*v0.z + v0.w*v0.w
           + v1.x*v1.x + v1.y*v1.y + v1.z*v1.z + v1.w*v1.w
           + v2.x*v2.x + v2.y*v2.y + v2.z*v2.z + v2.w*v2.w;
#pragma unroll
  for (int off = 32; off > 0; off >>= 1) ss += __shfl_xor(ss, off, 64);
  const float inv = 1.0f / sqrtf(ss * (1.0f / 576.0f) + 1e-6f);
  bf16* orow = xn + (size_t)row * KD;
  bf16x4 o0 = {(bf16)(v0.x*inv), (bf16)(v0.y*inv), (bf16)(v0.z*inv), (bf16)(v0.w*inv)};
  *(bf16x4*)(orow + lane * 4) = o0;
  bf16x4 o1 = {(bf16)(v1.x*inv), (bf16)(v1.y*inv), (bf16)(v1.z*inv), (bf16)(v1.w*inv)};
  *(bf16x4*)(orow + (lane + 64) * 4) = o1;
  if (lane < 16) {
    bf16x4 o2 = {(bf16)(v2.x*inv), (bf16)(v2.y*inv), (bf16)(v2.z*inv), (bf16)(v2.w*inv)};
    *(bf16x4*)(orow + (lane + 128) * 4) = o2;
  }
}

// ---------------- RoPE cos/sin table: [2048][32] each ----------------
__global__ void ropetab_k(float* __restrict__ ctab, float* __restrict__ stab) {
  const int s = blockIdx.x * blockDim.x + threadIdx.x;
  if (s >= 2048) return;
  const float l2r = 0.4152410118609203f;  // log2(10000)/32
#pragma unroll 1
  for (int i = 0; i < 32; ++i) {
    const float theta = exp2f(-(float)i * l2r);
    const float f = (float)s * theta;
    float sv, cv;
    sincosf(f, &sv, &cv);
    ctab[s * 32 + i] = cv;
    stab[s * 32 + i] = sv;
  }
}

// -------- weights -> bf16: Wcat = [Wq;Wkv] padded to 1792 rows; Wo padded to 640 --------
__global__ __launch_bounds__(256) void wconv_k(const float* __restrict__ Wq,
                                               const float* __restrict__ Wkv,
                                               const float* __restrict__ Wo,
                                               bf16* __restrict__ wcat,
                                               bf16* __restrict__ wo) {
  const int idx = blockIdx.x * 256 + threadIdx.x;   // grid covers 1792*576 exactly
  {
    const int row = idx / 576;
    float v = 0.f;
    if (row < 576)       v = Wq[idx];
    else if (row < 1728) v = Wkv[idx - 331776];
    wcat[idx] = (bf16)v;
  }
  if (idx < 640 * 576) {
    float v = (idx < 331776) ? Wo[idx] : 0.f;
    wo[idx] = (bf16)v;
  }
}

// ---------------- GEMM1 (QKV): 256x256, BK=64, 8 waves, barrier-min (R8: 81us) CONTROL ----
__global__ __launch_bounds__(512, 2) void gemm8p_k(const bf16* __restrict__ A,
                                                   const bf16* __restrict__ Bw,
                                                   bf16* __restrict__ C,
                                                   int ntiles) {
  extern __shared__ char smem[];
  const int tid  = threadIdx.x;
  const int lane = tid & 63;
  const int wv   = tid >> 6;
  const int nwg = gridDim.x;          // % 8 == 0
  const int cpx = nwg >> 3;
  const int swz = (blockIdx.x & 7) * cpx + (blockIdx.x >> 3);
  const int mt = swz / ntiles;
  const int nt = swz - mt * ntiles;
  const int wMl = (wv >> 2) << 7;
  const int wNl = (wv & 3) << 6;

  const bf16* Ab = A  + (size_t)mt * 256 * KD;
  const bf16* Bb = Bw + (size_t)nt * 256 * KD;

  int off[4];
#pragma unroll
  for (int u = 0; u < 2; ++u)
#pragma unroll
    for (int q = 0; q < 2; ++q) {
      const int c = u * 1024 + q * 512 + tid;
      const int row = c >> 3, slot = c & 7;
      const int ks = slot ^ (row & 7);
      off[u * 2 + q] = row * KD + ks * 8;
    }

  auto stage_unit = [&](int uu, int k0n, int bb) {
    const int u = uu & 1;
#pragma unroll
    for (int q = 0; q < 2; ++q) {
      const int c = u * 1024 + q * 512 + tid;
      if (uu < 2) gload_lds16(Ab + off[u * 2 + q] + k0n, smem + bb * 65536 + c * 16);
      else        gload_lds16(Bb + off[u * 2 + q] + k0n, smem + bb * 65536 + 32768 + c * 16);
    }
  };

  f32x4 acc[8][4];
#pragma unroll
  for (int i = 0; i < 8; ++i)
#pragma unroll
    for (int j = 0; j < 4; ++j) { acc[i][j][0]=0.f; acc[i][j][1]=0.f; acc[i][j][2]=0.f; acc[i][j][3]=0.f; }

#pragma unroll
  for (int uu = 0; uu < 4; ++uu) stage_unit(uu, 0, 0);

#pragma unroll 1
  for (int t = 0; t < 9; ++t) {
    const int cur = t & 1, nxt = cur ^ 1;
    const int k0n = (t + 1) * 64;
    if (t < 8) {
      stage_unit(0, k0n, nxt);
      stage_unit(1, k0n, nxt);
      asm volatile("s_waitcnt vmcnt(4)" ::: "memory");
    } else {
      asm volatile("s_waitcnt vmcnt(0)" ::: "memory");
    }
    BAR();
    const bf16* As = (const bf16*)(smem + cur * 65536);
    const bf16* Bs = (const bf16*)(smem + cur * 65536 + 32768);
    s16x8 bfrag[4][2];
#pragma unroll
    for (int p = 0; p < 4; ++p) {
      s16x8 afrag[2][2];
#pragma unroll
      for (int i2 = 0; i2 < 2; ++i2)
#pragma unroll
        for (int kk = 0; kk < 2; ++kk) {
          const int arow = wMl + (p * 2 + i2) * 16 + (lane & 15);
          const int aps  = ((kk << 2) + (lane >> 4)) ^ (arow & 7);
          afrag[i2][kk] = *(const s16x8*)(As + arow * 64 + aps * 8);
        }
      if (p == 0) {
#pragma unroll
        for (int j = 0; j < 4; ++j)
#pragma unroll
          for (int kk = 0; kk < 2; ++kk) {
            const int brow = wNl + j * 16 + (lane & 15);
            const int bps  = ((kk << 2) + (lane >> 4)) ^ (brow & 7);
            bfrag[j][kk] = *(const s16x8*)(Bs + brow * 64 + bps * 8);
          }
      }
      if (t < 8 && p < 2) stage_unit(2 + p, k0n, nxt);
      asm volatile("s_waitcnt lgkmcnt(0)" ::: "memory");
      SCHED0();
      __builtin_amdgcn_s_setprio(1);
#pragma unroll
      for (int i2 = 0; i2 < 2; ++i2)
#pragma unroll
        for (int j = 0; j < 4; ++j)
#pragma unroll
          for (int kk = 0; kk < 2; ++kk)
            acc[p * 2 + i2][j] = __builtin_amdgcn_mfma_f32_16x16x32_bf16(
                afrag[i2][kk], bfrag[j][kk], acc[p * 2 + i2][j], 0, 0, 0);
      __builtin_amdgcn_s_setprio(0);
      SCHED0();
    }
    BAR();
  }

  bf16* ep = (bf16*)(smem + wv * 9216);
  const size_t crow0 = (size_t)(mt * 256 + wMl);
  const int    ccol0 = nt * 256 + wNl;
#pragma unroll
  for (int half = 0; half < 2; ++half) {
    asm volatile("s_waitcnt lgkmcnt(0)" ::: "memory"); SCHED0();
#pragma unroll
    for (int i = 0; i < 4; ++i)
#pragma unroll
      for (int j = 0; j < 4; ++j)
#pragma unroll
        for (int r = 0; r < 4; ++r) {
          const int row = i * 16 + ((lane >> 4) << 2) + r;
          ep[row * 72 + j * 16 + (lane & 15)] = (bf16)acc[half * 4 + i][j][r];
        }
    asm volatile("s_waitcnt lgkmcnt(0)" ::: "memory"); SCHED0();
#pragma unroll
    for (int it = 0; it < 8; ++it) {
      const int c = it * 64 + lane;
      const int row = c >> 3, c8 = c & 7;
      s16x8 v = *(const s16x8*)(ep + row * 72 + c8 * 8);
      *(s16x8*)(C + (crow0 + half * 64 + row) * (size_t)N1P + ccol0 + c8 * 8) = v;
    }
  }
}

// ---------------- GEMM2 (O-proj + identity): main loop UNCHANGED; NEW coalesced epilogue ----
// Old epilogue: 4B scattered f32 stores + 4B scattered ident reads (64B segments).
// New: per-wave LDS transpose (16x64 f32 chunks, stride 68 pad, wave-private) ->
// f32x4 reads/stores in 256B segments for both ident and C.
__global__ __launch_bounds__(256) void gemm_o_k(const bf16* __restrict__ A,
                                                const bf16* __restrict__ Bw,
                                                float* __restrict__ C,
                                                const float* __restrict__ ident,
                                                int ntiles) {
  __shared__ bf16 smem2[2 * 128 * 64];
  bf16* As = smem2;
  bf16* Bs = smem2 + 128 * 64;
  const int tid  = threadIdx.x;
  const int lane = tid & 63;
  const int nwg = gridDim.x;
  const int cpx = nwg >> 3;
  const int swz = (blockIdx.x & 7) * cpx + (blockIdx.x >> 3);
  const int mt = swz / ntiles;
  const int nt = swz - mt * ntiles;
  const int wv = tid >> 6;
  const int wr = (wv >> 1) << 6;
  const int wc = (wv & 1) << 6;

  const size_t abase = (size_t)mt * 128 * KD;
  const size_t bbase = (size_t)nt * 128 * KD;

  f32x4 zero = {0.f, 0.f, 0.f, 0.f};
  f32x4 acc[4][4];
#pragma unroll
  for (int i = 0; i < 4; ++i)
#pragma unroll
    for (int j = 0; j < 4; ++j) acc[i][j] = zero;

  for (int kt = 0; kt < 9; ++kt) {
    const int k0 = kt * 64;
    __syncthreads();
#pragma unroll
    for (int r = 0; r < 4; ++r) {
      const int c   = r * 256 + tid;
      const int row = c >> 3;
      const int ks  = (c & 7) ^ (row & 7);
      gload_lds16(A + abase + (size_t)row * KD + k0 + ks * 8, As + c * 8);
    }
#pragma unroll
    for (int r = 0; r < 4; ++r) {
      const int c   = r * 256 + tid;
      const int row = c >> 3;
      const int ks  = (c & 7) ^ (row & 7);
      gload_lds16(Bw + bbase + (size_t)row * KD + k0 + ks * 8, Bs + c * 8);
    }
    __syncthreads();
#pragma unroll
    for (int kk = 0; kk < 2; ++kk) {
      s16x8 af[4], bq[4];
#pragma unroll
      for (int i = 0; i < 4; ++i) {
        const int arow = wr + i * 16 + (lane & 15);
        const int aps  = ((kk << 2) + (lane >> 4)) ^ (arow & 7);
        af[i] = *(const s16x8*)(As + arow * 64 + aps * 8);
      }
#pragma unroll
      for (int j = 0; j < 4; ++j) {
        const int brow = wc + j * 16 + (lane & 15);
        const int bps  = ((kk << 2) + (lane >> 4)) ^ (brow & 7);
        bq[j] = *(const s16x8*)(Bs + brow * 64 + bps * 8);
      }
#pragma unroll
      for (int i = 0; i < 4; ++i)
#pragma unroll
        for (int j = 0; j < 4; ++j)
          acc[i][j] = __builtin_amdgcn_mfma_f32_16x16x32_bf16(af[i], bq[j], acc[i][j], 0, 0, 0);
    }
  }

  // epilogue: all MFMA LDS reads done across all waves before reusing smem2
  __syncthreads();
  float* ep = (float*)smem2 + wv * (16 * 68);   // 4 waves x 4352B = 17.4KB < 32KB
  const int rgrp = lane >> 4;   // 0..3
  const int lc   = lane & 15;
  const bool colsOK = (nt * 128 + wc) < 576;    // whole 64-col wave chunk in range or not
#pragma unroll
  for (int i = 0; i < 4; ++i) {
#pragma unroll
    for (int j = 0; j < 4; ++j)
#pragma unroll
      for (int r = 0; r < 4; ++r)
        ep[(rgrp * 4 + r) * 68 + j * 16 + lc] = acc[i][j][r];
    asm volatile("s_waitcnt lgkmcnt(0)" ::: "memory"); SCHED0();
    if (colsOK) {
#pragma unroll
      for (int p = 0; p < 4; ++p) {
        const int rr  = p * 4 + rgrp;
        const int row = mt * 128 + wr + i * 16 + rr;
        const int col = nt * 128 + wc + lc * 4;
        f32x4 v = *(const f32x4*)(ep + rr * 68 + lc * 4);
        const float4 id = *(const float4*)(ident + (size_t)row * 576 + col);
        v[0] += id.x; v[1] += id.y; v[2] += id.z; v[3] += id.w;
        *(f32x4*)(C + (size_t)row * 576 + col) = v;
      }
    }
    asm volatile("s_waitcnt lgkmcnt(0)" ::: "memory"); SCHED0();  // reads done before next i overwrites
  }
}

// ---------------- attention v3: LDS-staged, coalesced ----------------
// Block = 256 thr stages 16 positions of qkv ([16][1800] bf16 LDS, rows padded ->
// pos-groups 4 banks apart; k/v reads broadcast across 9 workers). 16 workers/pos,
// workers 0..8 = heads. Converts the 256B-strided 16B global loads (25% bus) into
// 216x16B fully-coalesced global_load_lds chunks per row.
__global__ __launch_bounds__(256) void attn3_k(const bf16* __restrict__ qkv,
                                               const float* __restrict__ ctab,
                                               const float* __restrict__ stab,
                                               bf16* __restrict__ attn) {
  __shared__ bf16 lds[16 * 1800];
  const int tid = threadIdx.x;
  const int bs0 = blockIdx.x << 4;
  if (tid < 216) {   // 216 chunks of 16B = cols 0..1727 (q 576 + kv 1152)
#pragma unroll
    for (int row = 0; row < 16; ++row)
      gload_lds16(qkv + (size_t)(bs0 + row) * N1P + tid * 8, lds + row * 1800 + tid * 8);
  }
  __syncthreads();   // compiler drains vmcnt(0) before barrier -> staging visible

  const int pos = tid >> 4;
  const int w   = tid & 15;
  if (w >= 9) return;
  const int bs = bs0 + pos;
  const int s  = bs & 2047;
  const int b  = bs >> 11;
  const bf16* qrow = lds + pos * 1800;

  float q[64];
#pragma unroll
  for (int c = 0; c < 8; ++c) {
    bf16x8 v = *(const bf16x8*)(qrow + w * 64 + c * 8);
#pragma unroll
    for (int e = 0; e < 8; ++e) q[c * 8 + e] = (float)v[e];
  }
  const float* cr = ctab + s * 32;
  const float* sr = stab + s * 32;
#pragma unroll
  for (int i = 0; i < 32; ++i) {
    const float cv = cr[i], sv = sr[i];
    const float a = q[2 * i], bq_ = q[2 * i + 1];
    q[2 * i]     = a * cv - bq_ * sv;
    q[2 * i + 1] = a * sv + bq_ * cv;
  }
  const bf16* kvr = qrow + 576;
  float sc[9];
#pragma unroll
  for (int g = 0; g < 9; ++g) {
    const bf16* kg = kvr + g * 128;
    float d0 = 0.f, d1 = 0.f, d2 = 0.f, d3 = 0.f;
#pragma unroll
    for (int c = 0; c < 8; ++c) {
      bf16x8 v = *(const bf16x8*)(kg + c * 8);
      d0 += q[c*8+0] * (float)v[0];
      d1 += q[c*8+1] * (float)v[1];
      d2 += q[c*8+2] * (float)v[2];
      d3 += q[c*8+3] * (float)v[3];
      d0 += q[c*8+4] * (float)v[4];
      d1 += q[c*8+5] * (float)v[5];
      d2 += q[c*8+6] * (float)v[6];
      d3 += q[c*8+7] * (float)v[7];
    }
    sc[g] = (d0 + d1 + d2 + d3) * 0.125f;
  }
  float mx = sc[0];
#pragma unroll
  for (int g = 1; g < 9; ++g) mx = fmaxf(mx, sc[g]);
  float sum = 0.f;
#pragma unroll
  for (int g = 0; g < 9; ++g) { sc[g] = expf(sc[g] - mx); sum += sc[g]; }
  const float inv = 1.0f / sum;
#pragma unroll
  for (int g = 0; g < 9; ++g) sc[g] *= inv;

  bf16* orow = attn + ((size_t)((b * 9 + w) * 2048 + s)) * 64;
#pragma unroll
  for (int c = 0; c < 8; ++c) {
    float o[8];
#pragma unroll
    for (int e = 0; e < 8; ++e) o[e] = 0.f;
#pragma unroll
    for (int g = 0; g < 9; ++g) {
      bf16x8 v = *(const bf16x8*)(kvr + g * 128 + 64 + c * 8);
#pragma unroll
      for (int e = 0; e < 8; ++e) o[e] += sc[g] * (float)v[e];
    }
    bf16x8 ov;
#pragma unroll
    for (int e = 0; e < 8; ++e) ov[e] = (bf16)o[e];
    *(bf16x8*)(orow + c * 8) = ov;
  }
}

// ---------------- launch ----------------
extern "C" void kernel_launch(void* const* d_in, const int* in_sizes, int n_in,
                              void* d_out, int out_size, void* d_ws, size_t ws_size,
                              hipStream_t stream) {
  const float* x   = (const float*)d_in[0];
  const float* Wq  = (const float*)d_in[1];
  const float* Wkv = (const float*)d_in[2];
  const float* Wo  = (const float*)d_in[3];

  char* ws = (char*)d_ws;
  const size_t o_xn   = 0;                       // 32768*576*2 (xn, later attn)
  const size_t o_wcat = o_xn   + 37748736;
  const size_t o_wo   = o_wcat + 2064384;
  const size_t o_ct   = o_wo   + 737280;
  const size_t o_st   = o_ct   + 262144;
  const size_t o_qkv  = o_st   + 262144;
  const size_t need   = o_qkv  + 117440512;      // ~158.5 MB
  if (ws_size < need) return;

  bf16*  xn   = (bf16*)(ws + o_xn);
  bf16*  attn = (bf16*)(ws + o_xn);              // alias: xn dead after GEMM1
  bf16*  wcat = (bf16*)(ws + o_wcat);
  bf16*  wo   = (bf16*)(ws + o_wo);
  float* ctab = (float*)(ws + o_ct);
  float* stab = (float*)(ws + o_st);
  bf16*  qkv  = (bf16*)(ws + o_qkv);

  hipFuncSetAttribute((const void*)gemm8p_k,
                      hipFuncAttributeMaxDynamicSharedMemorySize, 131072);

  rmsnorm_k<<<8192, 256, 0, stream>>>(x, xn);
  ropetab_k<<<32, 64, 0, stream>>>(ctab, stab);
  wconv_k<<<4032, 256, 0, stream>>>(Wq, Wkv, Wo, wcat, wo);
  // QKV: M=32768, N=1792, K=576 -> 128 x 7 tiles of 256x256
  gemm8p_k<<<896, 512, 131072, stream>>>(xn, wcat, qkv, 7);
  // attention: 32768 positions / 16 per block
  attn3_k<<<2048, 256, 0, stream>>>(qkv, ctab, stab, attn);
  // O-proj + identity: M=32768, N=640(masked 576), K=576
  gemm_o_k<<<1280, 256, 0, stream>>>(attn, wo, (float*)d_out, x, 5);
}